// Round 1
// 2270.527 us; speedup vs baseline: 1.0018x; 1.0018x over previous
//
#include <hip/hip_runtime.h>
#include <cstdint>
#include <cstddef>

// ViT block (SAM-style windowed attention, 14x14 windows, decomposed rel-pos).
// I/O fp32 (per reference); internal GEMM/attention compute in bf16 MFMA, fp32 acc.
// hidden (final residual) kept full-fp32 in d_out.
// Pipeline: convert+transpose weights -> LN1(+window map, ->bf16) -> QKV GEMM ->
//           attention -> proj GEMM(+x residual, unpartition, ->fp32 d_out) ->
//           LN2 -> MLP1(gelu) -> MLP2(+hidden residual -> d_out fp32).
// R1: gemm_bt upgraded m93->m97 structure: global_load_lds width=16 staging into
//     linear (unpadded) LDS tiles; removes VGPR round-trip + staging addr VALU.

typedef unsigned short u16;
typedef __attribute__((ext_vector_type(8))) short bf16x8;   // 8 bf16 = 4 VGPRs
typedef __attribute__((ext_vector_type(4))) short bf16x4;   // 8B
typedef __attribute__((ext_vector_type(4))) float f32x4;

#define MFMA16(a,b,c) __builtin_amdgcn_mfma_f32_16x16x32_bf16(a,b,c,0,0,0)

__device__ __forceinline__ float bf2f(u16 u){
  union { unsigned int i; float f; } v; v.i = ((unsigned int)u) << 16; return v.f;
}
__device__ __forceinline__ u16 f2bf(float f){
  union { float f; unsigned int i; } v; v.f = f;
  unsigned int r = v.i + 0x7FFFu + ((v.i >> 16) & 1u);   // RNE
  return (u16)(r >> 16);
}
__device__ __forceinline__ f32x4 f4zero(){ f32x4 z; z[0]=z[1]=z[2]=z[3]=0.f; return z; }
__device__ __forceinline__ bf16x8 ld8(const u16* p){ return *reinterpret_cast<const bf16x8*>(p); }

// async global->LDS, 16B per lane. LDS dest = wave-uniform base + lane*16.
__device__ __forceinline__ void gld_lds16(const u16* g, u16* l){
  __builtin_amdgcn_global_load_lds(
      (const __attribute__((address_space(1))) unsigned int*)(g),
      (__attribute__((address_space(3))) unsigned int*)(l), 16, 0, 0);
}

// ------------------------------------------------ weight convert+transpose (fp32 -> bf16^T)
__global__ __launch_bounds__(256)
void conv_transpose(const float* __restrict__ in, u16* __restrict__ out, int R, int C)
{
  __shared__ float tile[32][33];
  int cb = C >> 5;
  int bx = blockIdx.x % cb, by = blockIdx.x / cb;
  int c0 = bx << 5, r0 = by << 5;
  int tx = threadIdx.x & 31, ty = threadIdx.x >> 5;   // ty 0..7
  #pragma unroll
  for (int k = 0; k < 4; k++)
    tile[ty + 8*k][tx] = in[(size_t)(r0 + ty + 8*k) * C + c0 + tx];
  __syncthreads();
  #pragma unroll
  for (int k = 0; k < 4; k++)
    out[(size_t)(c0 + ty + 8*k) * R + r0 + tx] = f2bf(tile[tx][ty + 8*k]);
}

// ------------------------------------------------ rel-pos table convert (fp32 -> bf16)
__global__ __launch_bounds__(256)
void conv_bf16(const float* __restrict__ a, const float* __restrict__ b,
               u16* __restrict__ oa, u16* __restrict__ ob, int n)
{
  int i = blockIdx.x * 256 + threadIdx.x;
  if (i < n){ oa[i] = f2bf(a[i]); ob[i] = f2bf(b[i]); }
}

// ------------------------------------------------ layernorm (fp32 in -> bf16 out)
// one wave per token (4 tokens/block). window_map=1: write rows window-partitioned.
__global__ __launch_bounds__(256)
void ln_kernel(const float* __restrict__ in, const float* __restrict__ g,
               const float* __restrict__ b, u16* __restrict__ out, int window_map)
{
  const int wv = threadIdx.x >> 6, lane = threadIdx.x & 63;
  const int token = blockIdx.x * 4 + wv;
  const float* row = in + (size_t)token * 768;
  float vals[12];
  float s = 0.f, s2 = 0.f;
  #pragma unroll
  for (int j = 0; j < 3; j++){
    float4 u = *reinterpret_cast<const float4*>(row + j*256 + lane*4);
    float t[4] = {u.x, u.y, u.z, u.w};
    #pragma unroll
    for (int e = 0; e < 4; e++){ vals[j*4+e] = t[e]; s += t[e]; s2 += t[e]*t[e]; }
  }
  #pragma unroll
  for (int m = 1; m < 64; m <<= 1){ s += __shfl_xor(s, m, 64); s2 += __shfl_xor(s2, m, 64); }
  float mu  = s  * (1.f/768.f);
  float var = s2 * (1.f/768.f) - mu*mu;
  float rs  = rsqrtf(var + 1e-5f);
  size_t orow = (size_t)token;
  if (window_map){
    int b_ = token / 3136, rem = token % 3136;
    int hh = rem / 56, ww = rem % 56;
    int win = ((b_ << 2) + hh/14)*4 + ww/14;
    orow = (size_t)win * 196 + (hh%14)*14 + (ww%14);
  }
  u16* op = out + orow * 768;
  #pragma unroll
  for (int j = 0; j < 3; j++){
    int cb = j*256 + lane*4;
    float4 gg = *reinterpret_cast<const float4*>(g + cb);
    float4 bb = *reinterpret_cast<const float4*>(b + cb);
    float gt[4] = {gg.x, gg.y, gg.z, gg.w};
    float bt[4] = {bb.x, bb.y, bb.z, bb.w};
    bf16x4 o;
    #pragma unroll
    for (int e = 0; e < 4; e++)
      o[e] = (short)f2bf((vals[j*4+e] - mu) * rs * gt[e] + bt[e]);
    *reinterpret_cast<bf16x4*>(op + cb) = o;
  }
}

// ------------------------------------------------ GEMM (m97-style)
// C[M,N] = A[M,K] @ Bt[N,K]^T (+bias +epilogue). 128x128 tile, 4 waves of 64x64.
// Staging: global_load_lds dwordx4 into LINEAR LDS tiles [128][32] (no pad; the
// unpadded layout is the verified m97 one — frag ds_read_b128 has min bank aliasing).
// Verified fragment layouts: A[m=lane&15][k=quad*8+j], B[k=quad*8+j][n=lane&15],
// D[row=quad*4+reg][col=lane&15].
enum { EPI_QKV = 0, EPI_PROJ = 1, EPI_GELU = 2, EPI_MLP2 = 3 };

__global__ __launch_bounds__(256)
void gemm_bt(const u16* __restrict__ A, const u16* __restrict__ Bt,
             const float* __restrict__ bias, const float* __restrict__ residf,
             void* __restrict__ outp, int M, int N, int K, int epi)
{
  __shared__ __align__(16) u16 As[128][32];
  __shared__ __align__(16) u16 Bs[128][32];
  const int nb = N >> 7;
  const int bm = blockIdx.x / nb, bn = blockIdx.x % nb;
  const int m0 = bm << 7, n0 = bn << 7;
  const int tid = threadIdx.x;
  const int wv = tid >> 6, lane = tid & 63;
  const int wm = (wv & 1) << 6, wn = (wv >> 1) << 6;
  const int q = lane >> 4, c = lane & 15;

  f32x4 acc[4][4];
  #pragma unroll
  for (int i = 0; i < 4; i++)
    #pragma unroll
    for (int j = 0; j < 4; j++) acc[i][j] = f4zero();

  // staging: wave wv owns rows [wv*32, wv*32+32) of each tile, 2 instrs of 16 rows.
  // instr writes LDS base + lane*16B -> row base+lane/4, cols (lane&3)*8..+8 (u16).
  const int r0 = (wv << 5) + (lane >> 2);
  const int cq = (lane & 3) << 3;
  const u16* pa = A  + (size_t)(m0 + r0) * K + cq;
  const u16* pb = Bt + (size_t)(n0 + r0) * K + cq;
  const size_t skip = (size_t)16 * K;          // 16 rows ahead
  u16* lA0 = &As[wv << 5][0];
  u16* lA1 = &As[(wv << 5) + 16][0];
  u16* lB0 = &Bs[wv << 5][0];
  u16* lB1 = &Bs[(wv << 5) + 16][0];

  for (int k0 = 0; k0 < K; k0 += 32){
    gld_lds16(pa + k0,        lA0);
    gld_lds16(pa + skip + k0, lA1);
    gld_lds16(pb + k0,        lB0);
    gld_lds16(pb + skip + k0, lB1);
    __syncthreads();                 // compiler drains vmcnt before barrier
    bf16x8 af[4], bfr[4];
    #pragma unroll
    for (int mi = 0; mi < 4; mi++) af[mi]  = ld8(&As[wm + mi*16 + c][q*8]);
    #pragma unroll
    for (int ni = 0; ni < 4; ni++) bfr[ni] = ld8(&Bs[wn + ni*16 + c][q*8]);
    #pragma unroll
    for (int mi = 0; mi < 4; mi++)
      #pragma unroll
      for (int ni = 0; ni < 4; ni++)
        acc[mi][ni] = MFMA16(af[mi], bfr[ni], acc[mi][ni]);
    __syncthreads();                 // LDS safe to overwrite next iter
  }

  // epilogue
  #pragma unroll
  for (int mi = 0; mi < 4; mi++){
    #pragma unroll
    for (int r = 0; r < 4; r++){
      int grow = m0 + wm + mi*16 + q*4 + r;
      size_t orow = (size_t)grow;
      if (epi == EPI_PROJ){   // window-order row -> standard (b,h,w) row
        int win = grow / 196, loc = grow % 196;
        int b_ = win >> 4, wr = win & 15;
        int hh = (wr >> 2) * 14 + loc / 14;
        int ww = (wr & 3)  * 14 + loc % 14;
        orow = (size_t)((b_ * 56 + hh) * 56 + ww);
      }
      #pragma unroll
      for (int ni = 0; ni < 4; ni++){
        int col = n0 + wn + ni*16 + c;
        float v = acc[mi][ni][r] + bias[col];
        if (epi == EPI_PROJ){           // + x (shortcut), fp32 out
          v += residf[orow * 768 + col];
          ((float*)outp)[orow * (size_t)N + col] = v;
        } else if (epi == EPI_MLP2){    // + hidden, fp32 out (in-place safe: same elem)
          v += residf[(size_t)grow * 768 + col];
          ((float*)outp)[orow * (size_t)N + col] = v;
        } else {
          if (epi == EPI_GELU) v = 0.5f * v * (1.f + erff(v * 0.70710678f));
          ((u16*)outp)[orow * (size_t)N + col] = f2bf(v);
        }
      }
    }
  }
}

// ------------------------------------------------ attention
// one block per (window, head). 4 waves; wave handles m-tiles {wv, wv+4, ...} of 13.
// Q/K frags direct from global (L1/L2-cached); V transposed into LDS; rel-pos bias
// via small MFMAs vs the 27x64 bf16 tables + LDS gather; P round-trips LDS (m120).
__global__ __launch_bounds__(256)
void attn_kernel(const u16* __restrict__ qkv, const u16* __restrict__ relh,
                 const u16* __restrict__ relw, u16* __restrict__ aout)
{
  __shared__ u16 Vt[64][232];          // [hd][token 0..223 +pad]; cols >=196 zeroed
  __shared__ u16 P[4][16*216 + 16];    // per-wave P tile, rows stride 216, 16-elem tail
  __shared__ u16 RB[4][16][56];        // per-wave bias: [row][dh 0..26 | 28+dw 0..26]
  const int blk = blockIdx.x;
  const int win = blk / 12, head = blk % 12;
  const int tid = threadIdx.x;
  const int wv = tid >> 6, lane = tid & 63;
  const int q = lane >> 4, c = lane & 15;
  const u16* base = qkv + (size_t)win * 196 * 2304 + head * 64;

  // zero V pad cols and P pad cols/tail
  for (int i = tid; i < 64*36; i += 256) Vt[i / 36][196 + i % 36] = 0;
  for (int i = tid; i < 4*144; i += 256){
    int w = i / 144, r = i % 144;
    int off = (r < 128) ? ((r >> 3) * 216 + 208 + (r & 7)) : (16*216 + (r - 128));
    P[w][off] = 0;
  }
  // load V transposed: Vt[hd][token]
  for (int i = tid; i < 196*8; i += 256){
    int t = i >> 3, h8 = (i & 7) << 3;
    bf16x8 v = ld8(base + (size_t)t * 2304 + 1536 + h8);
    #pragma unroll
    for (int j = 0; j < 8; j++) Vt[h8 + j][t] = (u16)v[j];
  }
  __syncthreads();

  const float scale = 0.125f;   // 64^-0.5
  for (int mt = wv; mt < 13; mt += 4){
    const int m0 = mt * 16;
    int qr = m0 + c; if (qr > 195) qr = 195;
    const u16* qrow = base + (size_t)qr * 2304;
    bf16x8 aq0 = ld8(qrow + q*8);
    bf16x8 aq1 = ld8(qrow + 32 + q*8);

    // S = q @ K^T  (13 n-tiles of 16 keys)
    f32x4 accs[13];
    #pragma unroll
    for (int nt = 0; nt < 13; nt++) accs[nt] = f4zero();
    #pragma unroll
    for (int nt = 0; nt < 13; nt++){
      int kt = nt*16 + c; if (kt > 195) kt = 195;
      const u16* krow = base + (size_t)kt * 2304 + 768;
      accs[nt] = MFMA16(aq0, ld8(krow + q*8), accs[nt]);
      accs[nt] = MFMA16(aq1, ld8(krow + 32 + q*8), accs[nt]);
    }

    // RB[row][dh] = q_row . rel_pos[dh]  (dh 0..26, 2 n-tiles)
    f32x4 rha[2], rwa[2];
    #pragma unroll
    for (int ntt = 0; ntt < 2; ntt++){
      int dh = ntt*16 + c; if (dh > 26) dh = 26;
      const u16* ph = relh + dh*64;
      const u16* pw = relw + dh*64;
      rha[ntt] = MFMA16(aq0, ld8(ph + q*8), f4zero());
      rha[ntt] = MFMA16(aq1, ld8(ph + 32 + q*8), rha[ntt]);
      rwa[ntt] = MFMA16(aq0, ld8(pw + q*8), f4zero());
      rwa[ntt] = MFMA16(aq1, ld8(pw + 32 + q*8), rwa[ntt]);
    }
    #pragma unroll
    for (int ntt = 0; ntt < 2; ntt++)
      #pragma unroll
      for (int r = 0; r < 4; r++){
        int col = ntt*16 + c;
        if (col < 27){
          RB[wv][q*4+r][col]      = f2bf(rha[ntt][r]);
          RB[wv][q*4+r][28 + col] = f2bf(rwa[ntt][r]);
        }
      }

    // bias + mask + softmax per row (rows q*4+r; cols per 16-lane group)
    #pragma unroll
    for (int r = 0; r < 4; r++){
      int it = m0 + q*4 + r; if (it > 195) it = 195;
      int hq = it / 14, wq = it % 14;
      float sv[13];
      float mx = -3e38f;
      #pragma unroll
      for (int nt = 0; nt < 13; nt++){
        int j = nt*16 + c;
        float x;
        if (j < 196){
          int hk = j / 14, wk = j % 14;
          x = accs[nt][r] * scale + bf2f(RB[wv][q*4+r][hq - hk + 13])
                                  + bf2f(RB[wv][q*4+r][28 + wq - wk + 13]);
        } else x = -3e38f;
        sv[nt] = x; mx = fmaxf(mx, x);
      }
      mx = fmaxf(mx, __shfl_xor(mx, 1, 64));
      mx = fmaxf(mx, __shfl_xor(mx, 2, 64));
      mx = fmaxf(mx, __shfl_xor(mx, 4, 64));
      mx = fmaxf(mx, __shfl_xor(mx, 8, 64));
      float sum = 0.f;
      #pragma unroll
      for (int nt = 0; nt < 13; nt++){ float p = __expf(sv[nt] - mx); sv[nt] = p; sum += p; }
      sum += __shfl_xor(sum, 1, 64); sum += __shfl_xor(sum, 2, 64);
      sum += __shfl_xor(sum, 4, 64); sum += __shfl_xor(sum, 8, 64);
      float is = 1.f / sum;
      #pragma unroll
      for (int nt = 0; nt < 13; nt++)
        P[wv][(q*4+r)*216 + nt*16 + c] = f2bf(sv[nt] * is);
    }

    // O = P @ V  (K padded to 224; P cols 208..215 zero, 216..223 hit zeroed Vt)
    f32x4 acco[4];
    #pragma unroll
    for (int nv = 0; nv < 4; nv++) acco[nv] = f4zero();
    #pragma unroll
    for (int ks = 0; ks < 7; ks++){
      bf16x8 ap = ld8(&P[wv][c*216 + ks*32 + q*8]);
      #pragma unroll
      for (int nv = 0; nv < 4; nv++){
        bf16x8 bv = ld8(&Vt[nv*16 + c][ks*32 + q*8]);
        acco[nv] = MFMA16(ap, bv, acco[nv]);
      }
    }
    #pragma unroll
    for (int nv = 0; nv < 4; nv++)
      #pragma unroll
      for (int r = 0; r < 4; r++){
        int it = m0 + q*4 + r;
        if (it < 196)
          aout[(size_t)(win*196 + it)*768 + head*64 + nv*16 + c] = f2bf(acco[nv][r]);
      }
  }
}

// ------------------------------------------------ launch
extern "C" void kernel_launch(void* const* d_in, const int* in_sizes, int n_in,
                              void* d_out, int out_size, void* d_ws, size_t ws_size,
                              hipStream_t stream)
{
  (void)in_sizes; (void)n_in; (void)out_size; (void)ws_size;
  const float* x      = (const float*)d_in[0];
  const float* n1g    = (const float*)d_in[1];
  const float* n1b    = (const float*)d_in[2];
  const float* qkv_w  = (const float*)d_in[3];
  const float* qkv_b  = (const float*)d_in[4];
  const float* proj_w = (const float*)d_in[5];
  const float* proj_b = (const float*)d_in[6];
  const float* relh   = (const float*)d_in[7];
  const float* relw   = (const float*)d_in[8];
  const float* n2g    = (const float*)d_in[9];
  const float* n2b    = (const float*)d_in[10];
  const float* lin1_w = (const float*)d_in[11];
  const float* lin1_b = (const float*)d_in[12];
  const float* lin2_w = (const float*)d_in[13];
  const float* lin2_b = (const float*)d_in[14];
  float* out = (float*)d_out;   // also serves as fp32 'hidden' buffer

  char* ws = (char*)d_ws;
  u16* qkvwt  = (u16*)(ws);                        //  3,538,944 B
  u16* projwt = (u16*)(ws +  3538944);             //  1,179,648 B
  u16* lin1wt = (u16*)(ws +  4718592);             //  4,718,592 B
  u16* lin2wt = (u16*)(ws +  9437184);             //  4,718,592 B
  u16* relhb  = (u16*)(ws + 14155776);             //      3,456 B
  u16* relwb  = (u16*)(ws + 14159232);             //      3,456 B
  u16* bufA   = (u16*)(ws + 14162688);             // 77,070,336 B: ln1out -> attnout -> normed
  u16* bufQ   = (u16*)(ws + 14162688 + (size_t)77070336); // 231,211,008 B: qkv -> m1 chunks
  // total ws usage: 322,444,032 B

  conv_transpose<<<(768/32)*(2304/32), 256, 0, stream>>>(qkv_w,  qkvwt, 768, 2304);
  conv_transpose<<<(768/32)*(768/32),  256, 0, stream>>>(proj_w, projwt, 768, 768);
  conv_transpose<<<(768/32)*(3072/32), 256, 0, stream>>>(lin1_w, lin1wt, 768, 3072);
  conv_transpose<<<(3072/32)*(768/32), 256, 0, stream>>>(lin2_w, lin2wt, 3072, 768);
  conv_bf16<<<(27*64 + 255)/256, 256, 0, stream>>>(relh, relw, relhb, relwb, 27*64);

  // LN1 (window-ordered bf16) -> QKV GEMM -> attention
  ln_kernel<<<12544, 256, 0, stream>>>(x, n1g, n1b, bufA, 1);
  gemm_bt<<<392*18, 256, 0, stream>>>(bufA, qkvwt, qkv_b, nullptr, bufQ,
                                      50176, 2304, 768, EPI_QKV);
  attn_kernel<<<3072, 256, 0, stream>>>(bufQ, relhb, relwb, bufA);
  // proj + residual -> hidden (fp32, in d_out)
  gemm_bt<<<392*6, 256, 0, stream>>>(bufA, projwt, proj_b, x, out,
                                     50176, 768, 768, EPI_PROJ);
  // LN2 -> MLP (2 halves; m1 reuses bufQ)
  ln_kernel<<<12544, 256, 0, stream>>>(out, n2g, n2b, bufA, 0);
  for (int h = 0; h < 2; h++){
    const u16* nrm = bufA + (size_t)h * 25088 * 768;
    float* hid     = out  + (size_t)h * 25088 * 768;
    gemm_bt<<<196*24, 256, 0, stream>>>(nrm, lin1wt, lin1_b, nullptr, bufQ,
                                        25088, 3072, 768, EPI_GELU);
    gemm_bt<<<196*6, 256, 0, stream>>>(bufQ, lin2wt, lin2_b, hid, hid,
                                       25088, 768, 3072, EPI_MLP2);
  }
}